// Round 7
// baseline (430.909 us; speedup 1.0000x reference)
//
#include <hip/hip_runtime.h>
#include <hip/hip_cooperative_groups.h>
#include <math.h>

namespace cg = cooperative_groups;

typedef unsigned short u16;
typedef unsigned int   u32;
typedef __attribute__((ext_vector_type(8))) short bf16x8;
typedef __attribute__((ext_vector_type(4))) float f32x4;

#define BATCH  32
#define SEQ    512
#define DM     512
#define SQE    (SEQ*DM)                  // 262144
#define NBE    ((size_t)BATCH*SQE)       // 8388608 elements

__device__ __forceinline__ u16 f2bf(float x) {
  union { float f; u32 i; } v; v.f = x;
  u32 r = v.i + 0x7fffu + ((v.i >> 16) & 1u);
  return (u16)(r >> 16);
}
__device__ __forceinline__ float bf2f(u16 u) {
  union { u32 i; float f; } v; v.i = ((u32)u) << 16; return v.f;
}
__device__ __forceinline__ float fast_tanh(float x) {
  float xc = fminf(fmaxf(x, -15.f), 15.f);
  float e  = __expf(2.f * xc);
  return (e - 1.f) * __builtin_amdgcn_rcpf(e + 1.f);
}

// async 16B/lane global->LDS (lds dest = wave-uniform base + lane*16)
__device__ __forceinline__ void async16(const void* g, void* l) {
  __builtin_amdgcn_global_load_lds(
      (const __attribute__((address_space(1))) void*)g,
      (__attribute__((address_space(3))) void*)l, 16, 0, 0);
}

#define MFMA(a, b, c) __builtin_amdgcn_mfma_f32_16x16x32_bf16((a), (b), (c), 0, 0, 0)

// C[128][128] += A[128 x 64*kttot] * B[128 x 64*kttot]^T  (R6 core, unchanged).
// BK=64, both-sides XOR swizzle, 2-phase dbuf, one __syncthreads per K-step.
__device__ __forceinline__ void gemm_bf16(
    const u16* Alo, const u16* Ahi, int ktlo, int kttot, int lda,
    const u16* B, int ldb,
    u16* sA, u16* sB, f32x4 acc[4][4])   // sA,sB: 2*128*64 elems (32 KB) each
{
  const int tid  = threadIdx.x;
  const int lane = tid & 63;
  const int wid  = tid >> 6;
  const int wm = (wid >> 1) * 64;
  const int wn = (wid & 1) * 64;
  const int lm = lane & 15;
  const int lq = lane >> 4;

  size_t aoq[4], boq[4];
#pragma unroll
  for (int q = 0; q < 4; ++q) {
    const int c  = tid + 256 * q;
    const int r  = c >> 3;
    const int kg = ((c & 7) ^ (r & 7)) * 8;
    aoq[q] = (size_t)r * lda + kg;
    boq[q] = (size_t)r * ldb + kg;
  }

#define STAGE_TILE(kt, h)                                                  \
  do {                                                                     \
    const u16* Ab = ((kt) < ktlo) ? (Alo + (size_t)(kt) * 64)              \
                                  : (Ahi + (size_t)((kt) - ktlo) * 64);    \
    const u16* Bb = B + (size_t)(kt) * 64;                                 \
    _Pragma("unroll")                                                      \
    for (int q = 0; q < 4; ++q) {                                          \
      u16* dA = sA + (h) * 8192 + (256 * q + wid * 64) * 8;                \
      u16* dB = sB + (h) * 8192 + (256 * q + wid * 64) * 8;                \
      async16(Ab + aoq[q], dA);                                            \
      async16(Bb + boq[q], dB);                                            \
    }                                                                      \
  } while (0)

  STAGE_TILE(0, 0);
  __syncthreads();
  int cur = 0;
  for (int kt = 0; kt < kttot; ++kt) {
    if (kt + 1 < kttot) STAGE_TILE(kt + 1, cur ^ 1);
    const u16* tA = sA + cur * 8192;
    const u16* tB = sB + cur * 8192;
#pragma unroll
    for (int kk = 0; kk < 2; ++kk) {
      bf16x8 af[4], bv[4];
#pragma unroll
      for (int i = 0; i < 4; ++i) {
        const int R = wm + i * 16 + lm;
        af[i] = *(const bf16x8*)(tA + R * 64 + ((kk * 4 + lq) ^ (R & 7)) * 8);
      }
#pragma unroll
      for (int j = 0; j < 4; ++j) {
        const int R = wn + j * 16 + lm;
        bv[j] = *(const bf16x8*)(tB + R * 64 + ((kk * 4 + lq) ^ (R & 7)) * 8);
      }
#pragma unroll
      for (int i = 0; i < 4; ++i)
#pragma unroll
        for (int j = 0; j < 4; ++j)
          acc[i][j] = MFMA(af[i], bv[j], acc[i][j]);
    }
    __syncthreads();
    cur ^= 1;
  }
#undef STAGE_TILE
}

// ---- phase 0: prep unit bx in [0,6400): fp32->bf16 P/W, E -> Ebf + EbfT ----
__device__ __forceinline__ void phase_prep(
    int bx, const float* P, const float* W, const float* E,
    u16* Pbf, u16* Wbf, u16* Ebf, u16* EbfT, u16* smem)
{
  const int tid = threadIdx.x;
  if (bx < 4352) {
    size_t base = (size_t)bx * 2048 + tid * 8;
    const float* s; u16* d;
    if (bx < 4096) { s = P + base; d = Pbf + base; }
    else { size_t o = base - (size_t)4096 * 2048; s = W + o; d = Wbf + o; }
    float4 a = *(const float4*)s;
    float4 b4 = *(const float4*)(s + 4);
    bf16x8 v;
    v[0] = (short)f2bf(a.x); v[1] = (short)f2bf(a.y);
    v[2] = (short)f2bf(a.z); v[3] = (short)f2bf(a.w);
    v[4] = (short)f2bf(b4.x); v[5] = (short)f2bf(b4.y);
    v[6] = (short)f2bf(b4.z); v[7] = (short)f2bf(b4.w);
    *(bf16x8*)d = v;
    return;
  }
  u16 (*sT)[72] = (u16(*)[72])smem;
  __syncthreads();                       // protect sT readers of prior unit
  const int e  = bx - 4352;              // 0..2047
  const int b  = e >> 6;
  const int s0 = ((e >> 3) & 7) * 64;
  const int d0 = (e & 7) * 64;
  const int r = tid >> 2, c = (tid & 3) * 16;
  const float* src = E + (size_t)b * SQE + (size_t)(s0 + r) * DM + d0 + c;
  float4 x0 = ((const float4*)src)[0];
  float4 x1 = ((const float4*)src)[1];
  float4 x2 = ((const float4*)src)[2];
  float4 x3 = ((const float4*)src)[3];
  float xs[16] = {x0.x,x0.y,x0.z,x0.w, x1.x,x1.y,x1.z,x1.w,
                  x2.x,x2.y,x2.z,x2.w, x3.x,x3.y,x3.z,x3.w};
  u16 v[16];
#pragma unroll
  for (int j = 0; j < 16; ++j) v[j] = f2bf(xs[j]);
  bf16x8 o0, o1;
#pragma unroll
  for (int j = 0; j < 8; ++j) { o0[j] = (short)v[j]; o1[j] = (short)v[8 + j]; }
  u16* dro = Ebf + (size_t)b * SQE + (size_t)(s0 + r) * DM + d0 + c;
  *(bf16x8*)dro = o0;
  *(bf16x8*)(dro + 8) = o1;
#pragma unroll
  for (int j = 0; j < 16; ++j) sT[c + j][r] = v[j];
  __syncthreads();
  const int dr = tid >> 2, sc = (tid & 3) * 16;
  bf16x8 t0, t1;
#pragma unroll
  for (int j = 0; j < 8; ++j) { t0[j] = (short)sT[dr][sc + j]; t1[j] = (short)sT[dr][sc + 8 + j]; }
  u16* dst = EbfT + (size_t)b * SQE + (size_t)(d0 + dr) * SEQ + s0 + sc;
  *(bf16x8*)dst = t0;
  *(bf16x8*)(dst + 8) = t1;
}

// ---- phase 1: Px = exp(Pbf @ Ebf^T * scale) bf16; row-sum partials --------
__device__ __forceinline__ void phase_scores(
    int bid, const u16* Pbf, const u16* Ebf, u16* Px, float* Rpart, u16* smem)
{
  u16* sA = smem; u16* sB = smem + 16384;
  const int mt = bid & 3, nt = (bid >> 2) & 3, b = bid >> 4;
  const u16* A  = Pbf + (size_t)b * SQE + (size_t)(mt * 128) * DM;
  const u16* Bp = Ebf + (size_t)b * SQE + (size_t)(nt * 128) * DM;
  f32x4 acc[4][4] = {};
  gemm_bf16(A, A, 8, 8, DM, Bp, DM, sA, sB, acc);

  const int tid = threadIdx.x, lane = tid & 63, wid = tid >> 6;
  const int wm = (wid >> 1) * 64, wn = (wid & 1) * 64;
  const int lm = lane & 15, lq = lane >> 4;
  const float scale = 0.044194173824159216f;  // 1/sqrt(512)
  u16* outp = Px + (size_t)b * SQE + (size_t)(mt * 128) * SEQ + nt * 128;
  float* rp = Rpart + (size_t)(nt * 2 + (wid & 1)) * 16384 + (size_t)b * SEQ + mt * 128;
#pragma unroll
  for (int i = 0; i < 4; ++i)
#pragma unroll
    for (int r = 0; r < 4; ++r) {
      const int row = wm + i * 16 + lq * 4 + r;
      float rs = 0.f;
#pragma unroll
      for (int j = 0; j < 4; ++j) {
        const float p = __expf(acc[i][j][r] * scale);
        outp[(size_t)row * SEQ + wn + j * 16 + lm] = f2bf(p);
        rs += p;
      }
      rs += __shfl_xor(rs, 1, 64);
      rs += __shfl_xor(rs, 2, 64);
      rs += __shfl_xor(rs, 4, 64);
      rs += __shfl_xor(rs, 8, 64);
      if (lm == 0) rp[row] = rs;           // non-atomic: (nt, wave-half) partial
    }
}

// ---- phase 2: ctx = (Px @ E)*inv; also writes out1 = Px*inv (v_norm fold) --
__device__ __forceinline__ void phase_ctx(
    int bid, const u16* Px, const u16* EbfT, const float* Rpart,
    u16* Ctx, float* out1, u16* smem)
{
  u16* sA = smem; u16* sB = smem + 16384;
  const int mt = bid & 3, nt = (bid >> 2) & 3, b = bid >> 4;
  const u16* A  = Px   + (size_t)b * SQE + (size_t)(mt * 128) * SEQ;
  const u16* Bp = EbfT + (size_t)b * SQE + (size_t)(nt * 128) * SEQ;
  f32x4 acc[4][4] = {};
  gemm_bf16(A, A, 8, 8, SEQ, Bp, SEQ, sA, sB, acc);

  const int tid = threadIdx.x, lane = tid & 63, wid = tid >> 6;
  const int wm = (wid >> 1) * 64, wn = (wid & 1) * 64;
  const int lm = lane & 15, lq = lane >> 4;
  float* sInv = (float*)smem;              // sA dead after gemm's last barrier
  if (tid < 128) {
    const size_t row = (size_t)b * SEQ + mt * 128 + tid;
    float s = 0.f;
#pragma unroll
    for (int p = 0; p < 8; ++p) s += Rpart[(size_t)p * 16384 + row];
    sInv[tid] = 1.0f / s;
  }
  __syncthreads();
  u16* outc = Ctx + (size_t)b * SQE + (size_t)(mt * 128) * DM + nt * 128;
#pragma unroll
  for (int i = 0; i < 4; ++i)
#pragma unroll
    for (int r = 0; r < 4; ++r) {
      const int rl = wm + i * 16 + lq * 4 + r;
      const float inv = sInv[rl];
#pragma unroll
      for (int j = 0; j < 4; ++j)
        outc[(size_t)rl * DM + wn + j * 16 + lm] = f2bf(acc[i][j][r] * inv);
    }
  // out1 tile: rows [mt*128..+128), cols [nt*128..+128)
  const int rr = tid >> 1, cb = (tid & 1) * 64;
  const float inv2 = sInv[rr];
  const u16* src = Px + (size_t)b * SQE + (size_t)(mt * 128 + rr) * SEQ + nt * 128 + cb;
  float* dst = out1 + (size_t)b * SQE + (size_t)(mt * 128 + rr) * SEQ + nt * 128 + cb;
#pragma unroll
  for (int j = 0; j < 8; ++j) {
    bf16x8 v = *(const bf16x8*)(src + j * 8);
    float4 o0 = {bf2f((u16)v[0]) * inv2, bf2f((u16)v[1]) * inv2,
                 bf2f((u16)v[2]) * inv2, bf2f((u16)v[3]) * inv2};
    float4 o1 = {bf2f((u16)v[4]) * inv2, bf2f((u16)v[5]) * inv2,
                 bf2f((u16)v[6]) * inv2, bf2f((u16)v[7]) * inv2};
    *(float4*)(dst + j * 8)     = o0;
    *(float4*)(dst + j * 8 + 4) = o1;
  }
}

// ---- phase 3: out0 = tanh([Pbf|Ctx] @ Wbf^T + bias) * mask -----------------
__device__ __forceinline__ void phase_final(
    int bid, const u16* Pbf, const u16* Ctx, const u16* Wbf,
    const float* Bi, const float* Mk, float* Out, u16* smem)
{
  u16* sA = smem; u16* sB = smem + 16384;
  const int mt = bid & 3, nt = (bid >> 2) & 3, b = bid >> 4;
  const u16* Alo = Pbf + (size_t)b * SQE + (size_t)(mt * 128) * DM;
  const u16* Ahi = Ctx + (size_t)b * SQE + (size_t)(mt * 128) * DM;
  const u16* Bp  = Wbf + (size_t)(nt * 128) * 1024;
  f32x4 acc[4][4] = {};
  gemm_bf16(Alo, Ahi, 8, 16, DM, Bp, 1024, sA, sB, acc);

  const int tid = threadIdx.x, lane = tid & 63, wid = tid >> 6;
  const int wm = (wid >> 1) * 64, wn = (wid & 1) * 64;
  const int lm = lane & 15, lq = lane >> 4;
  float* out = Out + (size_t)b * SQE + (size_t)(mt * 128) * DM + nt * 128;
#pragma unroll
  for (int i = 0; i < 4; ++i)
#pragma unroll
    for (int r = 0; r < 4; ++r) {
      const int row = wm + i * 16 + lq * 4 + r;
      const float mv = Mk[b * SEQ + mt * 128 + row];
#pragma unroll
      for (int j = 0; j < 4; ++j) {
        const int col = wn + j * 16 + lm;
        out[(size_t)row * DM + col] = fast_tanh(acc[i][j][r] + Bi[nt * 128 + col]) * mv;
      }
    }
}

// ---- single cooperative kernel: prep | scores | ctx+norm | final -----------
__global__ __launch_bounds__(256) void k_mega(
    const float* __restrict__ P, const float* __restrict__ W,
    const float* __restrict__ E, const float* __restrict__ Mk,
    const float* __restrict__ Bi,
    u16* Pbf, u16* Wbf, u16* Ebf, u16* EbfT,
    float* Rpart, u16* Px, u16* Ctx,
    float* out0, float* out1)
{
  __shared__ u16 smem[32768];              // 64 KB: sA | sB (2 blocks/CU)
  cg::grid_group g = cg::this_grid();
  for (int bx = blockIdx.x; bx < 6400; bx += 512)
    phase_prep(bx, P, W, E, Pbf, Wbf, Ebf, EbfT, smem);
  g.sync();
  phase_scores(blockIdx.x, Pbf, Ebf, Px, Rpart, smem);
  g.sync();
  phase_ctx(blockIdx.x, Px, EbfT, Rpart, Ctx, out1, smem);
  g.sync();
  phase_final(blockIdx.x, Pbf, Ctx, Wbf, Bi, Mk, out0, smem);
}

// ---- fallback: same phases as 4 ordinary kernels ---------------------------
__global__ __launch_bounds__(256) void k_p1(const float* P, const float* W, const float* E,
                                            u16* Pbf, u16* Wbf, u16* Ebf, u16* EbfT)
{
  __shared__ u16 sT[64 * 72];
  phase_prep(blockIdx.x, P, W, E, Pbf, Wbf, Ebf, EbfT, sT);
}
__global__ __launch_bounds__(256) void k_p2(const u16* Pbf, const u16* Ebf,
                                            u16* Px, float* Rpart)
{
  __shared__ u16 smem[32768];
  phase_scores(blockIdx.x, Pbf, Ebf, Px, Rpart, smem);
}
__global__ __launch_bounds__(256) void k_p3(const u16* Px, const u16* EbfT,
                                            const float* Rpart, u16* Ctx, float* out1)
{
  __shared__ u16 smem[32768];
  phase_ctx(blockIdx.x, Px, EbfT, Rpart, Ctx, out1, smem);
}
__global__ __launch_bounds__(256) void k_p4(const u16* Pbf, const u16* Ctx, const u16* Wbf,
                                            const float* Bi, const float* Mk, float* out0)
{
  __shared__ u16 smem[32768];
  phase_final(blockIdx.x, Pbf, Ctx, Wbf, Bi, Mk, out0, smem);
}

extern "C" void kernel_launch(void* const* d_in, const int* in_sizes, int n_in,
                              void* d_out, int out_size, void* d_ws, size_t ws_size,
                              hipStream_t stream)
{
  int i8a = -1, i8b = -1, iM = -1, iW = -1, iB = -1;
  for (int i = 0; i < n_in; ++i) {
    const int s = in_sizes[i];
    if (s == BATCH * SQE)      { if (i8a < 0) i8a = i; else i8b = i; }
    else if (s == BATCH * SEQ) iM = i;
    else if (s == DM * 1024)   iW = i;
    else if (s == DM)          iB = i;
  }
  if (i8a < 0) i8a = 0;
  if (i8b < 0) i8b = 1;
  if (iM < 0) iM = 2;
  if (iW < 0) iW = 3;
  if (iB < 0) iB = 4;
  const float* P  = (const float*)d_in[i8a];
  const float* E  = (const float*)d_in[i8b];
  const float* Mk = (const float*)d_in[iM];
  const float* W  = (const float*)d_in[iW];
  const float* Bi = (const float*)d_in[iB];

  float* out0 = (float*)d_out;                     // attention_masked (fp32)
  float* out1 = out0 + NBE;                        // attention_weights (fp32)

  // ws: Pbf | Ebf | EbfT | Ctx | Px (bf16, NBE each) | Wbf | Rpart
  u16*   Pbf   = (u16*)d_ws;
  u16*   Ebf   = Pbf  + NBE;
  u16*   EbfT  = Ebf  + NBE;
  u16*   Ctx   = EbfT + NBE;
  u16*   Px    = Ctx  + NBE;
  u16*   Wbf   = Px   + NBE;                 // 524288 elems
  float* Rpart = (float*)(Wbf + 524288);     // 8 * 16384 f32

  void* ka[] = {(void*)&P, (void*)&W, (void*)&E, (void*)&Mk, (void*)&Bi,
                (void*)&Pbf, (void*)&Wbf, (void*)&Ebf, (void*)&EbfT,
                (void*)&Rpart, (void*)&Px, (void*)&Ctx,
                (void*)&out0, (void*)&out1};
  hipError_t err = hipLaunchCooperativeKernel((const void*)k_mega, dim3(512),
                                              dim3(256), ka, 0, stream);
  if (err != hipSuccess) {
    (void)hipGetLastError();                 // clear; use ordinary launches
    k_p1<<<dim3(6400), dim3(256), 0, stream>>>(P, W, E, Pbf, Wbf, Ebf, EbfT);
    k_p2<<<dim3(512),  dim3(256), 0, stream>>>(Pbf, Ebf, Px, Rpart);
    k_p3<<<dim3(512),  dim3(256), 0, stream>>>(Px, EbfT, Rpart, Ctx, out1);
    k_p4<<<dim3(512),  dim3(256), 0, stream>>>(Pbf, Ctx, Wbf, Bi, Mk, out0);
  }
}

// Round 8
// 202.148 us; speedup vs baseline: 2.1317x; 2.1317x over previous
//
#include <hip/hip_runtime.h>
#include <math.h>

typedef unsigned short u16;
typedef unsigned int   u32;
typedef __attribute__((ext_vector_type(8))) short bf16x8;
typedef __attribute__((ext_vector_type(4))) float f32x4;

#define BATCH  32
#define SEQ    512
#define DM     512
#define SQE    (SEQ*DM)                  // 262144
#define NBE    ((size_t)BATCH*SQE)       // 8388608 elements

__device__ __forceinline__ u16 f2bf(float x) {
  union { float f; u32 i; } v; v.f = x;
  u32 r = v.i + 0x7fffu + ((v.i >> 16) & 1u);
  return (u16)(r >> 16);
}
__device__ __forceinline__ float bf2f(u16 u) {
  union { u32 i; float f; } v; v.i = ((u32)u) << 16; return v.f;
}
__device__ __forceinline__ float fast_tanh(float x) {
  float xc = fminf(fmaxf(x, -15.f), 15.f);
  float e  = __expf(2.f * xc);
  return (e - 1.f) * __builtin_amdgcn_rcpf(e + 1.f);
}

// async 16B/lane global->LDS (lds dest = wave-uniform base + lane*16)
__device__ __forceinline__ void async16(const void* g, void* l) {
  __builtin_amdgcn_global_load_lds(
      (const __attribute__((address_space(1))) void*)g,
      (__attribute__((address_space(3))) void*)l, 16, 0, 0);
}

#define MFMA(a, b, c) __builtin_amdgcn_mfma_f32_16x16x32_bf16((a), (b), (c), 0, 0, 0)

// C[128][128] += A[128 x 64*kttot] * B[128 x 64*kttot]^T  (R6 core, unchanged).
// BK=64, both-sides XOR swizzle, 2-phase dbuf, one __syncthreads per K-step.
__device__ __forceinline__ void gemm_bf16(
    const u16* Alo, const u16* Ahi, int ktlo, int kttot, int lda,
    const u16* B, int ldb,
    u16* sA, u16* sB, f32x4 acc[4][4])   // sA,sB: 2*128*64 elems (32 KB) each
{
  const int tid  = threadIdx.x;
  const int lane = tid & 63;
  const int wid  = tid >> 6;
  const int wm = (wid >> 1) * 64;
  const int wn = (wid & 1) * 64;
  const int lm = lane & 15;
  const int lq = lane >> 4;

  size_t aoq[4], boq[4];
#pragma unroll
  for (int q = 0; q < 4; ++q) {
    const int c  = tid + 256 * q;
    const int r  = c >> 3;
    const int kg = ((c & 7) ^ (r & 7)) * 8;
    aoq[q] = (size_t)r * lda + kg;
    boq[q] = (size_t)r * ldb + kg;
  }

#define STAGE_TILE(kt, h)                                                  \
  do {                                                                     \
    const u16* Ab = ((kt) < ktlo) ? (Alo + (size_t)(kt) * 64)              \
                                  : (Ahi + (size_t)((kt) - ktlo) * 64);    \
    const u16* Bb = B + (size_t)(kt) * 64;                                 \
    _Pragma("unroll")                                                      \
    for (int q = 0; q < 4; ++q) {                                          \
      u16* dA = sA + (h) * 8192 + (256 * q + wid * 64) * 8;                \
      u16* dB = sB + (h) * 8192 + (256 * q + wid * 64) * 8;                \
      async16(Ab + aoq[q], dA);                                            \
      async16(Bb + boq[q], dB);                                            \
    }                                                                      \
  } while (0)

  STAGE_TILE(0, 0);
  __syncthreads();
  int cur = 0;
  for (int kt = 0; kt < kttot; ++kt) {
    if (kt + 1 < kttot) STAGE_TILE(kt + 1, cur ^ 1);
    const u16* tA = sA + cur * 8192;
    const u16* tB = sB + cur * 8192;
#pragma unroll
    for (int kk = 0; kk < 2; ++kk) {
      bf16x8 af[4], bv[4];
#pragma unroll
      for (int i = 0; i < 4; ++i) {
        const int R = wm + i * 16 + lm;
        af[i] = *(const bf16x8*)(tA + R * 64 + ((kk * 4 + lq) ^ (R & 7)) * 8);
      }
#pragma unroll
      for (int j = 0; j < 4; ++j) {
        const int R = wn + j * 16 + lm;
        bv[j] = *(const bf16x8*)(tB + R * 64 + ((kk * 4 + lq) ^ (R & 7)) * 8);
      }
#pragma unroll
      for (int i = 0; i < 4; ++i)
#pragma unroll
        for (int j = 0; j < 4; ++j)
          acc[i][j] = MFMA(af[i], bv[j], acc[i][j]);
    }
    __syncthreads();
    cur ^= 1;
  }
#undef STAGE_TILE
}

// ---- prep: fp32->bf16 (P, W), E -> Ebf + EbfT ------------------------------
// blocks 0..4095: P | 4096..4351: W | 4352..6399: E
__global__ __launch_bounds__(256) void k_prep(const float* __restrict__ P,
                                              const float* __restrict__ W,
                                              const float* __restrict__ E,
                                              u16* __restrict__ Pbf,
                                              u16* __restrict__ Wbf,
                                              u16* __restrict__ Ebf,
                                              u16* __restrict__ EbfT)
{
  __shared__ u16 sT[64][72];
  const int bx  = blockIdx.x;
  const int tid = threadIdx.x;
  if (bx < 4352) {
    size_t base = (size_t)bx * 2048 + tid * 8;
    const float* s; u16* d;
    if (bx < 4096) { s = P + base; d = Pbf + base; }
    else { size_t o = base - (size_t)4096 * 2048; s = W + o; d = Wbf + o; }
    float4 a = *(const float4*)s;
    float4 b = *(const float4*)(s + 4);
    bf16x8 v;
    v[0] = (short)f2bf(a.x); v[1] = (short)f2bf(a.y);
    v[2] = (short)f2bf(a.z); v[3] = (short)f2bf(a.w);
    v[4] = (short)f2bf(b.x); v[5] = (short)f2bf(b.y);
    v[6] = (short)f2bf(b.z); v[7] = (short)f2bf(b.w);
    *(bf16x8*)d = v;
    return;
  }
  const int e  = bx - 4352;              // 0..2047
  const int b  = e >> 6;
  const int s0 = ((e >> 3) & 7) * 64;
  const int d0 = (e & 7) * 64;
  const int r = tid >> 2, c = (tid & 3) * 16;
  const float* src = E + (size_t)b * SQE + (size_t)(s0 + r) * DM + d0 + c;
  float4 x0 = ((const float4*)src)[0];
  float4 x1 = ((const float4*)src)[1];
  float4 x2 = ((const float4*)src)[2];
  float4 x3 = ((const float4*)src)[3];
  float xs[16] = {x0.x,x0.y,x0.z,x0.w, x1.x,x1.y,x1.z,x1.w,
                  x2.x,x2.y,x2.z,x2.w, x3.x,x3.y,x3.z,x3.w};
  u16 v[16];
#pragma unroll
  for (int j = 0; j < 16; ++j) v[j] = f2bf(xs[j]);
  bf16x8 o0, o1;
#pragma unroll
  for (int j = 0; j < 8; ++j) { o0[j] = (short)v[j]; o1[j] = (short)v[8 + j]; }
  u16* dro = Ebf + (size_t)b * SQE + (size_t)(s0 + r) * DM + d0 + c;
  *(bf16x8*)dro = o0;
  *(bf16x8*)(dro + 8) = o1;
#pragma unroll
  for (int j = 0; j < 16; ++j) sT[c + j][r] = v[j];
  __syncthreads();
  const int dr = tid >> 2, sc = (tid & 3) * 16;
  bf16x8 t0, t1;
#pragma unroll
  for (int j = 0; j < 8; ++j) { t0[j] = (short)sT[dr][sc + j]; t1[j] = (short)sT[dr][sc + 8 + j]; }
  u16* dst = EbfT + (size_t)b * SQE + (size_t)(d0 + dr) * SEQ + s0 + sc;
  *(bf16x8*)dst = t0;
  *(bf16x8*)(dst + 8) = t1;
}

// ---- scores+exp: Px = exp(Pbf @ Ebf^T * scale) bf16; non-atomic partials ---
// Rpart[p][b*SEQ+row], p = nt*2 + (wid&1): each slot written exactly once.
__global__ __launch_bounds__(256) void k_scores(const u16* __restrict__ Pbf,
                                                const u16* __restrict__ Ebf,
                                                u16* __restrict__ Px,
                                                float* __restrict__ Rpart)
{
  __shared__ u16 sA[2 * 128 * 64];
  __shared__ u16 sB[2 * 128 * 64];
  const int mt = blockIdx.x, nt = blockIdx.y, b = blockIdx.z;
  const u16* A  = Pbf + (size_t)b * SQE + (size_t)(mt * 128) * DM;
  const u16* Bp = Ebf + (size_t)b * SQE + (size_t)(nt * 128) * DM;
  f32x4 acc[4][4] = {};
  gemm_bf16(A, A, 8, 8, DM, Bp, DM, sA, sB, acc);

  const int tid = threadIdx.x, lane = tid & 63, wid = tid >> 6;
  const int wm = (wid >> 1) * 64, wn = (wid & 1) * 64;
  const int lm = lane & 15, lq = lane >> 4;
  const float scale = 0.044194173824159216f;  // 1/sqrt(512)
  u16* outp = Px + (size_t)b * SQE + (size_t)(mt * 128) * SEQ + nt * 128;
  float* rp = Rpart + (size_t)(nt * 2 + (wid & 1)) * 16384 + (size_t)b * SEQ + mt * 128;
#pragma unroll
  for (int i = 0; i < 4; ++i)
#pragma unroll
    for (int r = 0; r < 4; ++r) {
      const int row = wm + i * 16 + lq * 4 + r;
      float rs = 0.f;
#pragma unroll
      for (int j = 0; j < 4; ++j) {
        const float p = __expf(acc[i][j][r] * scale);
        outp[(size_t)row * SEQ + wn + j * 16 + lm] = f2bf(p);
        rs += p;
      }
      rs += __shfl_xor(rs, 1, 64);
      rs += __shfl_xor(rs, 2, 64);
      rs += __shfl_xor(rs, 4, 64);
      rs += __shfl_xor(rs, 8, 64);
      if (lm == 0) rp[row] = rs;
    }
}

// ---- ctx = (Px @ E)*inv via EbfT; also writes out1 = Px*inv (v_norm fold) --
__global__ __launch_bounds__(256) void k_context(const u16* __restrict__ Px,
                                                 const u16* __restrict__ EbfT,
                                                 const float* __restrict__ Rpart,
                                                 u16* __restrict__ Ctx,
                                                 float* __restrict__ out1)
{
  __shared__ u16 sA[2 * 128 * 64];
  __shared__ u16 sB[2 * 128 * 64];
  const int mt = blockIdx.x, nt = blockIdx.y, b = blockIdx.z;
  const u16* A  = Px   + (size_t)b * SQE + (size_t)(mt * 128) * SEQ;
  const u16* Bp = EbfT + (size_t)b * SQE + (size_t)(nt * 128) * SEQ;
  f32x4 acc[4][4] = {};
  gemm_bf16(A, A, 8, 8, SEQ, Bp, SEQ, sA, sB, acc);

  const int tid = threadIdx.x, lane = tid & 63, wid = tid >> 6;
  const int wm = (wid >> 1) * 64, wn = (wid & 1) * 64;
  const int lm = lane & 15, lq = lane >> 4;
  float* sInv = (float*)sA;                // sA dead after gemm's last barrier
  if (tid < 128) {
    const size_t row = (size_t)b * SEQ + mt * 128 + tid;
    float s = 0.f;
#pragma unroll
    for (int p = 0; p < 8; ++p) s += Rpart[(size_t)p * 16384 + row];
    sInv[tid] = 1.0f / s;
  }
  __syncthreads();
  u16* outc = Ctx + (size_t)b * SQE + (size_t)(mt * 128) * DM + nt * 128;
#pragma unroll
  for (int i = 0; i < 4; ++i)
#pragma unroll
    for (int r = 0; r < 4; ++r) {
      const int rl = wm + i * 16 + lq * 4 + r;
      const float inv = sInv[rl];
#pragma unroll
      for (int j = 0; j < 4; ++j)
        outc[(size_t)rl * DM + wn + j * 16 + lm] = f2bf(acc[i][j][r] * inv);
    }
  // out1 tile: rows [mt*128..+128), cols [nt*128..+128)
  const int rr = tid >> 1, cb = (tid & 1) * 64;
  const float inv2 = sInv[rr];
  const u16* src = Px + (size_t)b * SQE + (size_t)(mt * 128 + rr) * SEQ + nt * 128 + cb;
  float* dst = out1 + (size_t)b * SQE + (size_t)(mt * 128 + rr) * SEQ + nt * 128 + cb;
#pragma unroll
  for (int j = 0; j < 8; ++j) {
    bf16x8 v = *(const bf16x8*)(src + j * 8);
    float4 o0 = {bf2f((u16)v[0]) * inv2, bf2f((u16)v[1]) * inv2,
                 bf2f((u16)v[2]) * inv2, bf2f((u16)v[3]) * inv2};
    float4 o1 = {bf2f((u16)v[4]) * inv2, bf2f((u16)v[5]) * inv2,
                 bf2f((u16)v[6]) * inv2, bf2f((u16)v[7]) * inv2};
    *(float4*)(dst + j * 8)     = o0;
    *(float4*)(dst + j * 8 + 4) = o1;
  }
}

// ---- out = tanh([Pbf|Ctx] @ Wbf^T + bias) * mask -> fp32 out0 --------------
__global__ __launch_bounds__(256) void k_final(const u16* __restrict__ Pbf,
                                               const u16* __restrict__ Ctx,
                                               const u16* __restrict__ Wbf,
                                               const float* __restrict__ bias,
                                               const float* __restrict__ mask,
                                               float* __restrict__ Out)
{
  __shared__ u16 sA[2 * 128 * 64];
  __shared__ u16 sB[2 * 128 * 64];
  const int mt = blockIdx.x, nt = blockIdx.y, b = blockIdx.z;
  const u16* Alo = Pbf + (size_t)b * SQE + (size_t)(mt * 128) * DM;
  const u16* Ahi = Ctx + (size_t)b * SQE + (size_t)(mt * 128) * DM;
  const u16* Bp  = Wbf + (size_t)(nt * 128) * 1024;
  f32x4 acc[4][4] = {};
  gemm_bf16(Alo, Ahi, 8, 16, DM, Bp, 1024, sA, sB, acc);

  const int tid = threadIdx.x, lane = tid & 63, wid = tid >> 6;
  const int wm = (wid >> 1) * 64, wn = (wid & 1) * 64;
  const int lm = lane & 15, lq = lane >> 4;
  float* out = Out + (size_t)b * SQE + (size_t)(mt * 128) * DM + nt * 128;
#pragma unroll
  for (int i = 0; i < 4; ++i)
#pragma unroll
    for (int r = 0; r < 4; ++r) {
      const int row = wm + i * 16 + lq * 4 + r;
      const float mv = mask[b * SEQ + mt * 128 + row];
#pragma unroll
      for (int j = 0; j < 4; ++j) {
        const int col = wn + j * 16 + lm;
        out[(size_t)row * DM + col] = fast_tanh(acc[i][j][r] + bias[nt * 128 + col]) * mv;
      }
    }
}

extern "C" void kernel_launch(void* const* d_in, const int* in_sizes, int n_in,
                              void* d_out, int out_size, void* d_ws, size_t ws_size,
                              hipStream_t stream)
{
  int i8a = -1, i8b = -1, iM = -1, iW = -1, iB = -1;
  for (int i = 0; i < n_in; ++i) {
    const int s = in_sizes[i];
    if (s == BATCH * SQE)      { if (i8a < 0) i8a = i; else i8b = i; }
    else if (s == BATCH * SEQ) iM = i;
    else if (s == DM * 1024)   iW = i;
    else if (s == DM)          iB = i;
  }
  if (i8a < 0) i8a = 0;
  if (i8b < 0) i8b = 1;
  if (iM < 0) iM = 2;
  if (iW < 0) iW = 3;
  if (iB < 0) iB = 4;
  const float* P  = (const float*)d_in[i8a];
  const float* E  = (const float*)d_in[i8b];
  const float* Mk = (const float*)d_in[iM];
  const float* W  = (const float*)d_in[iW];
  const float* Bi = (const float*)d_in[iB];

  float* out0 = (float*)d_out;                     // attention_masked (fp32)
  float* out1 = out0 + NBE;                        // attention_weights (fp32)

  // ws: Pbf | Ebf | EbfT | Ctx | Px (bf16, NBE each) | Wbf | Rpart
  u16*   Pbf   = (u16*)d_ws;
  u16*   Ebf   = Pbf  + NBE;
  u16*   EbfT  = Ebf  + NBE;
  u16*   Ctx   = EbfT + NBE;
  u16*   Px    = Ctx  + NBE;
  u16*   Wbf   = Px   + NBE;                 // 524288 elems
  float* Rpart = (float*)(Wbf + 524288);     // 8 * 16384 f32 (fully overwritten)

  dim3 blk(256);
  dim3 gg(4, 4, BATCH);
  k_prep   <<<dim3(6400), blk, 0, stream>>>(P, W, E, Pbf, Wbf, Ebf, EbfT);
  k_scores <<<gg, blk, 0, stream>>>(Pbf, Ebf, Px, Rpart);
  k_context<<<gg, blk, 0, stream>>>(Px, EbfT, Rpart, Ctx, out1);
  k_final  <<<gg, blk, 0, stream>>>(Pbf, Ctx, Wbf, Bi, Mk, out0);
}

// Round 9
// 192.384 us; speedup vs baseline: 2.2398x; 1.0508x over previous
//
#include <hip/hip_runtime.h>
#include <math.h>

typedef unsigned short u16;
typedef unsigned int   u32;
typedef __attribute__((ext_vector_type(8))) short bf16x8;
typedef __attribute__((ext_vector_type(4))) float f32x4;

#define BATCH  32
#define SEQ    512
#define DM     512
#define SQE    (SEQ*DM)                  // 262144
#define NBE    ((size_t)BATCH*SQE)       // 8388608 elements

__device__ __forceinline__ u16 f2bf(float x) {
  union { float f; u32 i; } v; v.f = x;
  u32 r = v.i + 0x7fffu + ((v.i >> 16) & 1u);
  return (u16)(r >> 16);
}
__device__ __forceinline__ float bf2f(u16 u) {
  union { u32 i; float f; } v; v.i = ((u32)u) << 16; return v.f;
}
__device__ __forceinline__ float fast_tanh(float x) {
  float xc = fminf(fmaxf(x, -15.f), 15.f);
  float e  = __expf(2.f * xc);
  return (e - 1.f) * __builtin_amdgcn_rcpf(e + 1.f);
}

// async 16B/lane global->LDS (lds dest = wave-uniform base + lane*16)
__device__ __forceinline__ void async16(const void* g, void* l) {
  __builtin_amdgcn_global_load_lds(
      (const __attribute__((address_space(1))) void*)g,
      (__attribute__((address_space(3))) void*)l, 16, 0, 0);
}

#define MFMA(a, b, c) __builtin_amdgcn_mfma_f32_16x16x32_bf16((a), (b), (c), 0, 0, 0)

// T1 XCD-chunked decode: 512 blocks, 8 XCDs, 64 blocks/XCD contiguous.
// Each XCD gets 4 complete batches (16 tiles each): A/B panels L2-resident.
__device__ __forceinline__ void xcd_decode(int& mt, int& nt, int& b) {
  const int fid = (int)blockIdx.x;             // 0..511
  const int swz = (fid & 7) * 64 + (fid >> 3); // bijective (512 % 8 == 0)
  mt = swz & 3; nt = (swz >> 2) & 3; b = swz >> 4;
}

// C[128][128] += A[128 x 64*kttot] * B[128 x 64*kttot]^T  (R6 core, unchanged).
// BK=64, both-sides XOR swizzle, 2-phase dbuf, one __syncthreads per K-step.
__device__ __forceinline__ void gemm_bf16(
    const u16* Alo, const u16* Ahi, int ktlo, int kttot, int lda,
    const u16* B, int ldb,
    u16* sA, u16* sB, f32x4 acc[4][4])   // sA,sB: 2*128*64 elems (32 KB) each
{
  const int tid  = threadIdx.x;
  const int lane = tid & 63;
  const int wid  = tid >> 6;
  const int wm = (wid >> 1) * 64;
  const int wn = (wid & 1) * 64;
  const int lm = lane & 15;
  const int lq = lane >> 4;

  size_t aoq[4], boq[4];
#pragma unroll
  for (int q = 0; q < 4; ++q) {
    const int c  = tid + 256 * q;
    const int r  = c >> 3;
    const int kg = ((c & 7) ^ (r & 7)) * 8;
    aoq[q] = (size_t)r * lda + kg;
    boq[q] = (size_t)r * ldb + kg;
  }

#define STAGE_TILE(kt, h)                                                  \
  do {                                                                     \
    const u16* Ab = ((kt) < ktlo) ? (Alo + (size_t)(kt) * 64)              \
                                  : (Ahi + (size_t)((kt) - ktlo) * 64);    \
    const u16* Bb = B + (size_t)(kt) * 64;                                 \
    _Pragma("unroll")                                                      \
    for (int q = 0; q < 4; ++q) {                                          \
      u16* dA = sA + (h) * 8192 + (256 * q + wid * 64) * 8;                \
      u16* dB = sB + (h) * 8192 + (256 * q + wid * 64) * 8;                \
      async16(Ab + aoq[q], dA);                                            \
      async16(Bb + boq[q], dB);                                            \
    }                                                                      \
  } while (0)

  STAGE_TILE(0, 0);
  __syncthreads();
  int cur = 0;
  for (int kt = 0; kt < kttot; ++kt) {
    if (kt + 1 < kttot) STAGE_TILE(kt + 1, cur ^ 1);
    const u16* tA = sA + cur * 8192;
    const u16* tB = sB + cur * 8192;
#pragma unroll
    for (int kk = 0; kk < 2; ++kk) {
      bf16x8 af[4], bv[4];
#pragma unroll
      for (int i = 0; i < 4; ++i) {
        const int R = wm + i * 16 + lm;
        af[i] = *(const bf16x8*)(tA + R * 64 + ((kk * 4 + lq) ^ (R & 7)) * 8);
      }
#pragma unroll
      for (int j = 0; j < 4; ++j) {
        const int R = wn + j * 16 + lm;
        bv[j] = *(const bf16x8*)(tB + R * 64 + ((kk * 4 + lq) ^ (R & 7)) * 8);
      }
#pragma unroll
      for (int i = 0; i < 4; ++i)
#pragma unroll
        for (int j = 0; j < 4; ++j)
          acc[i][j] = MFMA(af[i], bv[j], acc[i][j]);
    }
    __syncthreads();
    cur ^= 1;
  }
#undef STAGE_TILE
}

// ---- prep: fp32->bf16 (P, W), E -> Ebf + EbfT ------------------------------
// blocks 0..4095: P | 4096..4351: W | 4352..6399: E
__global__ __launch_bounds__(256) void k_prep(const float* __restrict__ P,
                                              const float* __restrict__ W,
                                              const float* __restrict__ E,
                                              u16* __restrict__ Pbf,
                                              u16* __restrict__ Wbf,
                                              u16* __restrict__ Ebf,
                                              u16* __restrict__ EbfT)
{
  __shared__ u16 sT[64][72];
  const int bx  = blockIdx.x;
  const int tid = threadIdx.x;
  if (bx < 4352) {
    size_t base = (size_t)bx * 2048 + tid * 8;
    const float* s; u16* d;
    if (bx < 4096) { s = P + base; d = Pbf + base; }
    else { size_t o = base - (size_t)4096 * 2048; s = W + o; d = Wbf + o; }
    float4 a = *(const float4*)s;
    float4 b = *(const float4*)(s + 4);
    bf16x8 v;
    v[0] = (short)f2bf(a.x); v[1] = (short)f2bf(a.y);
    v[2] = (short)f2bf(a.z); v[3] = (short)f2bf(a.w);
    v[4] = (short)f2bf(b.x); v[5] = (short)f2bf(b.y);
    v[6] = (short)f2bf(b.z); v[7] = (short)f2bf(b.w);
    *(bf16x8*)d = v;
    return;
  }
  const int e  = bx - 4352;              // 0..2047
  const int b  = e >> 6;
  const int s0 = ((e >> 3) & 7) * 64;
  const int d0 = (e & 7) * 64;
  const int r = tid >> 2, c = (tid & 3) * 16;
  const float* src = E + (size_t)b * SQE + (size_t)(s0 + r) * DM + d0 + c;
  float4 x0 = ((const float4*)src)[0];
  float4 x1 = ((const float4*)src)[1];
  float4 x2 = ((const float4*)src)[2];
  float4 x3 = ((const float4*)src)[3];
  float xs[16] = {x0.x,x0.y,x0.z,x0.w, x1.x,x1.y,x1.z,x1.w,
                  x2.x,x2.y,x2.z,x2.w, x3.x,x3.y,x3.z,x3.w};
  u16 v[16];
#pragma unroll
  for (int j = 0; j < 16; ++j) v[j] = f2bf(xs[j]);
  bf16x8 o0, o1;
#pragma unroll
  for (int j = 0; j < 8; ++j) { o0[j] = (short)v[j]; o1[j] = (short)v[8 + j]; }
  u16* dro = Ebf + (size_t)b * SQE + (size_t)(s0 + r) * DM + d0 + c;
  *(bf16x8*)dro = o0;
  *(bf16x8*)(dro + 8) = o1;
#pragma unroll
  for (int j = 0; j < 16; ++j) sT[c + j][r] = v[j];
  __syncthreads();
  const int dr = tid >> 2, sc = (tid & 3) * 16;
  bf16x8 t0, t1;
#pragma unroll
  for (int j = 0; j < 8; ++j) { t0[j] = (short)sT[dr][sc + j]; t1[j] = (short)sT[dr][sc + 8 + j]; }
  u16* dst = EbfT + (size_t)b * SQE + (size_t)(d0 + dr) * SEQ + s0 + sc;
  *(bf16x8*)dst = t0;
  *(bf16x8*)(dst + 8) = t1;
}

// ---- scores+exp: Px = exp(Pbf @ Ebf^T * scale) bf16; non-atomic partials ---
// Rpart[p][b*SEQ+row], p = nt*2 + (wid&1): each slot written exactly once.
__global__ __launch_bounds__(256) void k_scores(const u16* __restrict__ Pbf,
                                                const u16* __restrict__ Ebf,
                                                u16* __restrict__ Px,
                                                float* __restrict__ Rpart)
{
  __shared__ u16 sA[2 * 128 * 64];
  __shared__ u16 sB[2 * 128 * 64];
  int mt, nt, b;
  xcd_decode(mt, nt, b);
  const u16* A  = Pbf + (size_t)b * SQE + (size_t)(mt * 128) * DM;
  const u16* Bp = Ebf + (size_t)b * SQE + (size_t)(nt * 128) * DM;
  f32x4 acc[4][4] = {};
  gemm_bf16(A, A, 8, 8, DM, Bp, DM, sA, sB, acc);

  const int tid = threadIdx.x, lane = tid & 63, wid = tid >> 6;
  const int wm = (wid >> 1) * 64, wn = (wid & 1) * 64;
  const int lm = lane & 15, lq = lane >> 4;
  const float scale = 0.044194173824159216f;  // 1/sqrt(512)
  u16* outp = Px + (size_t)b * SQE + (size_t)(mt * 128) * SEQ + nt * 128;
  float* rp = Rpart + (size_t)(nt * 2 + (wid & 1)) * 16384 + (size_t)b * SEQ + mt * 128;
#pragma unroll
  for (int i = 0; i < 4; ++i)
#pragma unroll
    for (int r = 0; r < 4; ++r) {
      const int row = wm + i * 16 + lq * 4 + r;
      float rs = 0.f;
#pragma unroll
      for (int j = 0; j < 4; ++j) {
        const float p = __expf(acc[i][j][r] * scale);
        outp[(size_t)row * SEQ + wn + j * 16 + lm] = f2bf(p);
        rs += p;
      }
      rs += __shfl_xor(rs, 1, 64);
      rs += __shfl_xor(rs, 2, 64);
      rs += __shfl_xor(rs, 4, 64);
      rs += __shfl_xor(rs, 8, 64);
      if (lm == 0) rp[row] = rs;
    }
}

// ---- ctx = (Px @ E)*inv via EbfT; also writes out1 = Px*inv (v_norm fold) --
__global__ __launch_bounds__(256) void k_context(const u16* __restrict__ Px,
                                                 const u16* __restrict__ EbfT,
                                                 const float* __restrict__ Rpart,
                                                 u16* __restrict__ Ctx,
                                                 float* __restrict__ out1)
{
  __shared__ u16 sA[2 * 128 * 64];
  __shared__ u16 sB[2 * 128 * 64];
  int mt, nt, b;
  xcd_decode(mt, nt, b);
  const u16* A  = Px   + (size_t)b * SQE + (size_t)(mt * 128) * SEQ;
  const u16* Bp = EbfT + (size_t)b * SQE + (size_t)(nt * 128) * SEQ;
  f32x4 acc[4][4] = {};
  gemm_bf16(A, A, 8, 8, SEQ, Bp, SEQ, sA, sB, acc);

  const int tid = threadIdx.x, lane = tid & 63, wid = tid >> 6;
  const int wm = (wid >> 1) * 64, wn = (wid & 1) * 64;
  const int lm = lane & 15, lq = lane >> 4;
  float* sInv = (float*)sA;                // sA dead after gemm's last barrier
  if (tid < 128) {
    const size_t row = (size_t)b * SEQ + mt * 128 + tid;
    float s = 0.f;
#pragma unroll
    for (int p = 0; p < 8; ++p) s += Rpart[(size_t)p * 16384 + row];
    sInv[tid] = 1.0f / s;
  }
  __syncthreads();
  u16* outc = Ctx + (size_t)b * SQE + (size_t)(mt * 128) * DM + nt * 128;
#pragma unroll
  for (int i = 0; i < 4; ++i)
#pragma unroll
    for (int r = 0; r < 4; ++r) {
      const int rl = wm + i * 16 + lq * 4 + r;
      const float inv = sInv[rl];
#pragma unroll
      for (int j = 0; j < 4; ++j)
        outc[(size_t)rl * DM + wn + j * 16 + lm] = f2bf(acc[i][j][r] * inv);
    }
  // out1 tile: rows [mt*128..+128), cols [nt*128..+128)
  const int rr = tid >> 1, cb = (tid & 1) * 64;
  const float inv2 = sInv[rr];
  const u16* src = Px + (size_t)b * SQE + (size_t)(mt * 128 + rr) * SEQ + nt * 128 + cb;
  float* dst = out1 + (size_t)b * SQE + (size_t)(mt * 128 + rr) * SEQ + nt * 128 + cb;
#pragma unroll
  for (int j = 0; j < 8; ++j) {
    bf16x8 v = *(const bf16x8*)(src + j * 8);
    float4 o0 = {bf2f((u16)v[0]) * inv2, bf2f((u16)v[1]) * inv2,
                 bf2f((u16)v[2]) * inv2, bf2f((u16)v[3]) * inv2};
    float4 o1 = {bf2f((u16)v[4]) * inv2, bf2f((u16)v[5]) * inv2,
                 bf2f((u16)v[6]) * inv2, bf2f((u16)v[7]) * inv2};
    *(float4*)(dst + j * 8)     = o0;
    *(float4*)(dst + j * 8 + 4) = o1;
  }
}

// ---- out = tanh([Pbf|Ctx] @ Wbf^T + bias) * mask -> fp32 out0 --------------
__global__ __launch_bounds__(256) void k_final(const u16* __restrict__ Pbf,
                                               const u16* __restrict__ Ctx,
                                               const u16* __restrict__ Wbf,
                                               const float* __restrict__ bias,
                                               const float* __restrict__ mask,
                                               float* __restrict__ Out)
{
  __shared__ u16 sA[2 * 128 * 64];
  __shared__ u16 sB[2 * 128 * 64];
  int mt, nt, b;
  xcd_decode(mt, nt, b);
  const u16* Alo = Pbf + (size_t)b * SQE + (size_t)(mt * 128) * DM;
  const u16* Ahi = Ctx + (size_t)b * SQE + (size_t)(mt * 128) * DM;
  const u16* Bp  = Wbf + (size_t)(nt * 128) * 1024;
  f32x4 acc[4][4] = {};
  gemm_bf16(Alo, Ahi, 8, 16, DM, Bp, 1024, sA, sB, acc);

  const int tid = threadIdx.x, lane = tid & 63, wid = tid >> 6;
  const int wm = (wid >> 1) * 64, wn = (wid & 1) * 64;
  const int lm = lane & 15, lq = lane >> 4;
  float* out = Out + (size_t)b * SQE + (size_t)(mt * 128) * DM + nt * 128;
#pragma unroll
  for (int i = 0; i < 4; ++i)
#pragma unroll
    for (int r = 0; r < 4; ++r) {
      const int row = wm + i * 16 + lq * 4 + r;
      const float mv = mask[b * SEQ + mt * 128 + row];
#pragma unroll
      for (int j = 0; j < 4; ++j) {
        const int col = wn + j * 16 + lm;
        out[(size_t)row * DM + col] = fast_tanh(acc[i][j][r] + bias[nt * 128 + col]) * mv;
      }
    }
}

extern "C" void kernel_launch(void* const* d_in, const int* in_sizes, int n_in,
                              void* d_out, int out_size, void* d_ws, size_t ws_size,
                              hipStream_t stream)
{
  int i8a = -1, i8b = -1, iM = -1, iW = -1, iB = -1;
  for (int i = 0; i < n_in; ++i) {
    const int s = in_sizes[i];
    if (s == BATCH * SQE)      { if (i8a < 0) i8a = i; else i8b = i; }
    else if (s == BATCH * SEQ) iM = i;
    else if (s == DM * 1024)   iW = i;
    else if (s == DM)          iB = i;
  }
  if (i8a < 0) i8a = 0;
  if (i8b < 0) i8b = 1;
  if (iM < 0) iM = 2;
  if (iW < 0) iW = 3;
  if (iB < 0) iB = 4;
  const float* P  = (const float*)d_in[i8a];
  const float* E  = (const float*)d_in[i8b];
  const float* Mk = (const float*)d_in[iM];
  const float* W  = (const float*)d_in[iW];
  const float* Bi = (const float*)d_in[iB];

  float* out0 = (float*)d_out;                     // attention_masked (fp32)
  float* out1 = out0 + NBE;                        // attention_weights (fp32)

  // ws: Pbf | Ebf | EbfT | Ctx | Px (bf16, NBE each) | Wbf | Rpart
  u16*   Pbf   = (u16*)d_ws;
  u16*   Ebf   = Pbf  + NBE;
  u16*   EbfT  = Ebf  + NBE;
  u16*   Ctx   = EbfT + NBE;
  u16*   Px    = Ctx  + NBE;
  u16*   Wbf   = Px   + NBE;                 // 524288 elems
  float* Rpart = (float*)(Wbf + 524288);     // 8 * 16384 f32 (fully overwritten)

  dim3 blk(256);
  k_prep   <<<dim3(6400), blk, 0, stream>>>(P, W, E, Pbf, Wbf, Ebf, EbfT);
  k_scores <<<dim3(512), blk, 0, stream>>>(Pbf, Ebf, Px, Rpart);
  k_context<<<dim3(512), blk, 0, stream>>>(Px, EbfT, Rpart, Ctx, out1);
  k_final  <<<dim3(512), blk, 0, stream>>>(Pbf, Ctx, Wbf, Bi, Mk, out0);
}